// Round 1
// baseline (1195.338 us; speedup 1.0000x reference)
//
#include <hip/hip_runtime.h>

#define N_NODES 50000
#define N_EDGES 800000
#define DIM 96
#define NPB 32  // nodes per block in output kernel

// ---------------------------------------------------------------------------
// Scatter: one thread per (edge, 4-dim group). 24 groups per edge.
// unsafeAtomicAdd -> native global_atomic_add_f32 (no CAS loop).
// ---------------------------------------------------------------------------
__global__ __launch_bounds__(256) void scatter_k(
    const float* __restrict__ x,
    const int* __restrict__ ei,   // [2, N_EDGES] int32: row0=src, row1=tgt
    float* __restrict__ agg,      // [N_NODES, DIM] zero-initialized
    float* __restrict__ deg)      // [N_NODES] zero-initialized
{
    const int GROUPS = DIM / 4;  // 24
    int tid = blockIdx.x * 256 + threadIdx.x;
    if (tid >= N_EDGES * GROUPS) return;
    int e = tid / GROUPS;
    int g = tid - e * GROUPS;
    int s = ei[e];
    int t = ei[N_EDGES + e];
    float4 v = *reinterpret_cast<const float4*>(x + (size_t)s * DIM + g * 4);
    float* o = agg + (size_t)t * DIM + g * 4;
    unsafeAtomicAdd(o + 0, v.x);
    unsafeAtomicAdd(o + 1, v.y);
    unsafeAtomicAdd(o + 2, v.z);
    unsafeAtomicAdd(o + 3, v.w);
    if (g == 0) unsafeAtomicAdd(deg + t, 1.0f);
}

// ---------------------------------------------------------------------------
// Output: out = x @ Wself^T + mean @ Wneigh^T + bself + bneigh
// Block: 256 threads, 32 nodes. LDS: B (W^T, stride-97 padded, reused for
// both matrices in two k-phases) + A = [x | mean] rows.
// Thread (tx,ty): rows ty*8..ty*8+7, cols {tx, tx+64 if tx<32}.
// ---------------------------------------------------------------------------
__global__ __launch_bounds__(256) void sage_out_k(
    const float* __restrict__ x,
    const float* __restrict__ agg,
    const float* __restrict__ deg,
    const float* __restrict__ Wself,
    const float* __restrict__ bself,
    const float* __restrict__ Wneigh,
    const float* __restrict__ bneigh,
    float* __restrict__ out)
{
    __shared__ float Bs[96 * 97];     // 37,248 B : Bs[k*97+j] = W[j][k]
    __shared__ float As[NPB * 192];   // 24,576 B : As[r*192 + {k | 96+k}]
    const int tid = threadIdx.x;
    const int node0 = blockIdx.x * NPB;

    // ---- Stage A: x rows and mean rows (float4, coalesced) ----
    for (int idx = tid; idx < NPB * 24; idx += 256) {
        int r  = idx / 24;
        int c4 = idx - r * 24;
        int node = node0 + r;
        float4 xv = make_float4(0.f, 0.f, 0.f, 0.f);
        float4 mv = make_float4(0.f, 0.f, 0.f, 0.f);
        if (node < N_NODES) {
            xv = *reinterpret_cast<const float4*>(x + (size_t)node * DIM + c4 * 4);
            float4 av = *reinterpret_cast<const float4*>(agg + (size_t)node * DIM + c4 * 4);
            float inv = 1.0f / fmaxf(deg[node], 1.0f);
            mv = make_float4(av.x * inv, av.y * inv, av.z * inv, av.w * inv);
        }
        *reinterpret_cast<float4*>(As + r * 192 + c4 * 4)      = xv;
        *reinterpret_cast<float4*>(As + r * 192 + 96 + c4 * 4) = mv;
    }

    // ---- Stage B phase 1: Wself^T ----
    for (int idx = tid; idx < 96 * 96; idx += 256) {
        int j = idx / 96;
        int k = idx - j * 96;
        Bs[k * 97 + j] = Wself[idx];   // write bank (k+j)%32: conflict-free
    }
    __syncthreads();

    const int tx = tid & 63;
    const int ty = tid >> 6;
    const bool has2 = (tx < 32);
    const int j1 = tx + 64;

    float acc0[8], acc1[8];
#pragma unroll
    for (int r = 0; r < 8; r++) { acc0[r] = 0.f; acc1[r] = 0.f; }

    // ---- Phase 1: k-loop over x-part ----
    for (int k = 0; k < 96; k += 4) {
        float b0[4], b1[4];
#pragma unroll
        for (int u = 0; u < 4; u++) {
            b0[u] = Bs[(k + u) * 97 + tx];
            b1[u] = has2 ? Bs[(k + u) * 97 + j1] : 0.0f;
        }
#pragma unroll
        for (int r = 0; r < 8; r++) {
            const float4 a = *reinterpret_cast<const float4*>(As + (ty * 8 + r) * 192 + k);
            acc0[r] = fmaf(a.x, b0[0], acc0[r]);
            acc0[r] = fmaf(a.y, b0[1], acc0[r]);
            acc0[r] = fmaf(a.z, b0[2], acc0[r]);
            acc0[r] = fmaf(a.w, b0[3], acc0[r]);
            acc1[r] = fmaf(a.x, b1[0], acc1[r]);
            acc1[r] = fmaf(a.y, b1[1], acc1[r]);
            acc1[r] = fmaf(a.z, b1[2], acc1[r]);
            acc1[r] = fmaf(a.w, b1[3], acc1[r]);
        }
    }
    __syncthreads();

    // ---- Stage B phase 2: Wneigh^T ----
    for (int idx = tid; idx < 96 * 96; idx += 256) {
        int j = idx / 96;
        int k = idx - j * 96;
        Bs[k * 97 + j] = Wneigh[idx];
    }
    __syncthreads();

    // ---- Phase 2: k-loop over mean-part ----
    for (int k = 0; k < 96; k += 4) {
        float b0[4], b1[4];
#pragma unroll
        for (int u = 0; u < 4; u++) {
            b0[u] = Bs[(k + u) * 97 + tx];
            b1[u] = has2 ? Bs[(k + u) * 97 + j1] : 0.0f;
        }
#pragma unroll
        for (int r = 0; r < 8; r++) {
            const float4 a = *reinterpret_cast<const float4*>(As + (ty * 8 + r) * 192 + 96 + k);
            acc0[r] = fmaf(a.x, b0[0], acc0[r]);
            acc0[r] = fmaf(a.y, b0[1], acc0[r]);
            acc0[r] = fmaf(a.z, b0[2], acc0[r]);
            acc0[r] = fmaf(a.w, b0[3], acc0[r]);
            acc1[r] = fmaf(a.x, b1[0], acc1[r]);
            acc1[r] = fmaf(a.y, b1[1], acc1[r]);
            acc1[r] = fmaf(a.z, b1[2], acc1[r]);
            acc1[r] = fmaf(a.w, b1[3], acc1[r]);
        }
    }

    // ---- Epilogue: bias + store ----
    float bias0 = bself[tx] + bneigh[tx];
    float bias1 = has2 ? (bself[j1] + bneigh[j1]) : 0.0f;
#pragma unroll
    for (int r = 0; r < 8; r++) {
        int node = node0 + ty * 8 + r;
        if (node < N_NODES) {
            out[(size_t)node * DIM + tx] = acc0[r] + bias0;
            if (has2) out[(size_t)node * DIM + j1] = acc1[r] + bias1;
        }
    }
}

extern "C" void kernel_launch(void* const* d_in, const int* in_sizes, int n_in,
                              void* d_out, int out_size, void* d_ws, size_t ws_size,
                              hipStream_t stream) {
    const float* x      = (const float*)d_in[0];
    const int*   ei     = (const int*)d_in[1];
    const float* Wself  = (const float*)d_in[2];
    const float* bself  = (const float*)d_in[3];
    const float* Wneigh = (const float*)d_in[4];
    const float* bneigh = (const float*)d_in[5];
    float* out = (float*)d_out;

    float* agg = (float*)d_ws;                       // N_NODES*DIM floats
    float* deg = agg + (size_t)N_NODES * DIM;        // N_NODES floats

    size_t zero_bytes = ((size_t)N_NODES * DIM + N_NODES) * sizeof(float);
    hipMemsetAsync(d_ws, 0, zero_bytes, stream);

    const int scatter_threads = N_EDGES * (DIM / 4);
    scatter_k<<<(scatter_threads + 255) / 256, 256, 0, stream>>>(x, ei, agg, deg);

    sage_out_k<<<(N_NODES + NPB - 1) / NPB, 256, 0, stream>>>(
        x, agg, deg, Wself, bself, Wneigh, bneigh, out);
}

// Round 2
// 402.217 us; speedup vs baseline: 2.9719x; 2.9719x over previous
//
#include <hip/hip_runtime.h>

#define N_NODES 50000
#define N_EDGES 800000
#define DIM 96
#define NPB 32     // nodes per block in output kernel
#define PADN 50176 // N_NODES rounded up (alignment-friendly region size)

// ---------------------------------------------------------------------------
// K1: count degrees (int atomics)
// ---------------------------------------------------------------------------
__global__ __launch_bounds__(256) void count_k(
    const int* __restrict__ ei, int* __restrict__ cnt)
{
    int e = blockIdx.x * 256 + threadIdx.x;
    if (e >= N_EDGES) return;
    int t = ei[N_EDGES + e];
    atomicAdd(&cnt[t], 1);
}

// ---------------------------------------------------------------------------
// K2: single-block exclusive scan over 50K degrees -> row_off[N+1], cursor[N]
// ---------------------------------------------------------------------------
__global__ __launch_bounds__(1024) void scan_k(
    const int* __restrict__ cnt, int* __restrict__ row_off, int* __restrict__ cursor)
{
    __shared__ int sums[1024];
    const int tid = threadIdx.x;
    const int C = (N_NODES + 1023) / 1024;  // 49
    int start = tid * C;
    int end = start + C; if (end > N_NODES) end = N_NODES;
    if (start > N_NODES) start = N_NODES;

    int s = 0;
    for (int i = start; i < end; i++) s += cnt[i];
    sums[tid] = s;
    __syncthreads();
    // Hillis-Steele inclusive scan, 10 steps
    for (int off = 1; off < 1024; off <<= 1) {
        int v = (tid >= off) ? sums[tid - off] : 0;
        __syncthreads();
        sums[tid] += v;
        __syncthreads();
    }
    int run = (tid > 0) ? sums[tid - 1] : 0;  // exclusive prefix of this chunk
    for (int i = start; i < end; i++) {
        row_off[i] = run;
        cursor[i]  = run;
        run += cnt[i];
    }
    if (tid == 1023) row_off[N_NODES] = sums[1023];
}

// ---------------------------------------------------------------------------
// K3: bucket edges into CSR (int atomics on cursors)
// ---------------------------------------------------------------------------
__global__ __launch_bounds__(256) void bucket_k(
    const int* __restrict__ ei, int* __restrict__ cursor, int* __restrict__ edge_src)
{
    int e = blockIdx.x * 256 + threadIdx.x;
    if (e >= N_EDGES) return;
    int s = ei[e];
    int t = ei[N_EDGES + e];
    int pos = atomicAdd(&cursor[t], 1);
    edge_src[pos] = s;
}

// ---------------------------------------------------------------------------
// K4: gather-sum + mean. 24 threads per node (one float4 column each);
// block = 192 threads = 8 nodes. Per neighbor: 24 lanes x 16B = 384B
// contiguous read of an LLC-resident x row.
// ---------------------------------------------------------------------------
__global__ __launch_bounds__(192) void gather_mean_k(
    const float* __restrict__ x,
    const int* __restrict__ row_off,
    const int* __restrict__ edge_src,
    float* __restrict__ mean)
{
    const int tid = threadIdx.x;
    const int g = tid / 24;        // node group within block
    const int l = tid - g * 24;    // float4 column 0..23
    const int node = blockIdx.x * 8 + g;
    if (node >= N_NODES) return;

    const int beg = row_off[node];
    const int end = row_off[node + 1];
    float4 acc = make_float4(0.f, 0.f, 0.f, 0.f);
    for (int i = beg; i < end; i++) {
        int s = edge_src[i];
        float4 v = *reinterpret_cast<const float4*>(x + (size_t)s * DIM + l * 4);
        acc.x += v.x; acc.y += v.y; acc.z += v.z; acc.w += v.w;
    }
    float inv = (end > beg) ? 1.0f / (float)(end - beg) : 0.0f;
    acc.x *= inv; acc.y *= inv; acc.z *= inv; acc.w *= inv;
    *reinterpret_cast<float4*>(mean + (size_t)node * DIM + l * 4) = acc;
}

// ---------------------------------------------------------------------------
// K5: out = x @ Wself^T + mean @ Wneigh^T + bself + bneigh
// Same structure as round 1 (division removed — mean is precomputed).
// ---------------------------------------------------------------------------
__global__ __launch_bounds__(256) void sage_out_k(
    const float* __restrict__ x,
    const float* __restrict__ mean,
    const float* __restrict__ Wself,
    const float* __restrict__ bself,
    const float* __restrict__ Wneigh,
    const float* __restrict__ bneigh,
    float* __restrict__ out)
{
    __shared__ float Bs[96 * 97];     // Bs[k*97+j] = W[j][k]
    __shared__ float As[NPB * 192];   // As[r*192 + {k | 96+k}]
    const int tid = threadIdx.x;
    const int node0 = blockIdx.x * NPB;

    // ---- Stage A: x rows and mean rows (float4, coalesced) ----
    for (int idx = tid; idx < NPB * 24; idx += 256) {
        int r  = idx / 24;
        int c4 = idx - r * 24;
        int node = node0 + r;
        float4 xv = make_float4(0.f, 0.f, 0.f, 0.f);
        float4 mv = make_float4(0.f, 0.f, 0.f, 0.f);
        if (node < N_NODES) {
            xv = *reinterpret_cast<const float4*>(x + (size_t)node * DIM + c4 * 4);
            mv = *reinterpret_cast<const float4*>(mean + (size_t)node * DIM + c4 * 4);
        }
        *reinterpret_cast<float4*>(As + r * 192 + c4 * 4)      = xv;
        *reinterpret_cast<float4*>(As + r * 192 + 96 + c4 * 4) = mv;
    }

    // ---- Stage B phase 1: Wself^T ----
    for (int idx = tid; idx < 96 * 96; idx += 256) {
        int j = idx / 96;
        int k = idx - j * 96;
        Bs[k * 97 + j] = Wself[idx];
    }
    __syncthreads();

    const int tx = tid & 63;
    const int ty = tid >> 6;
    const bool has2 = (tx < 32);
    const int j1 = tx + 64;

    float acc0[8], acc1[8];
#pragma unroll
    for (int r = 0; r < 8; r++) { acc0[r] = 0.f; acc1[r] = 0.f; }

    // ---- Phase 1: k-loop over x-part ----
    for (int k = 0; k < 96; k += 4) {
        float b0[4], b1[4];
#pragma unroll
        for (int u = 0; u < 4; u++) {
            b0[u] = Bs[(k + u) * 97 + tx];
            b1[u] = has2 ? Bs[(k + u) * 97 + j1] : 0.0f;
        }
#pragma unroll
        for (int r = 0; r < 8; r++) {
            const float4 a = *reinterpret_cast<const float4*>(As + (ty * 8 + r) * 192 + k);
            acc0[r] = fmaf(a.x, b0[0], acc0[r]);
            acc0[r] = fmaf(a.y, b0[1], acc0[r]);
            acc0[r] = fmaf(a.z, b0[2], acc0[r]);
            acc0[r] = fmaf(a.w, b0[3], acc0[r]);
            acc1[r] = fmaf(a.x, b1[0], acc1[r]);
            acc1[r] = fmaf(a.y, b1[1], acc1[r]);
            acc1[r] = fmaf(a.z, b1[2], acc1[r]);
            acc1[r] = fmaf(a.w, b1[3], acc1[r]);
        }
    }
    __syncthreads();

    // ---- Stage B phase 2: Wneigh^T ----
    for (int idx = tid; idx < 96 * 96; idx += 256) {
        int j = idx / 96;
        int k = idx - j * 96;
        Bs[k * 97 + j] = Wneigh[idx];
    }
    __syncthreads();

    // ---- Phase 2: k-loop over mean-part ----
    for (int k = 0; k < 96; k += 4) {
        float b0[4], b1[4];
#pragma unroll
        for (int u = 0; u < 4; u++) {
            b0[u] = Bs[(k + u) * 97 + tx];
            b1[u] = has2 ? Bs[(k + u) * 97 + j1] : 0.0f;
        }
#pragma unroll
        for (int r = 0; r < 8; r++) {
            const float4 a = *reinterpret_cast<const float4*>(As + (ty * 8 + r) * 192 + 96 + k);
            acc0[r] = fmaf(a.x, b0[0], acc0[r]);
            acc0[r] = fmaf(a.y, b0[1], acc0[r]);
            acc0[r] = fmaf(a.z, b0[2], acc0[r]);
            acc0[r] = fmaf(a.w, b0[3], acc0[r]);
            acc1[r] = fmaf(a.x, b1[0], acc1[r]);
            acc1[r] = fmaf(a.y, b1[1], acc1[r]);
            acc1[r] = fmaf(a.z, b1[2], acc1[r]);
            acc1[r] = fmaf(a.w, b1[3], acc1[r]);
        }
    }

    // ---- Epilogue: bias + store ----
    float bias0 = bself[tx] + bneigh[tx];
    float bias1 = has2 ? (bself[j1] + bneigh[j1]) : 0.0f;
#pragma unroll
    for (int r = 0; r < 8; r++) {
        int node = node0 + ty * 8 + r;
        if (node < N_NODES) {
            out[(size_t)node * DIM + tx] = acc0[r] + bias0;
            if (has2) out[(size_t)node * DIM + j1] = acc1[r] + bias1;
        }
    }
}

extern "C" void kernel_launch(void* const* d_in, const int* in_sizes, int n_in,
                              void* d_out, int out_size, void* d_ws, size_t ws_size,
                              hipStream_t stream) {
    const float* x      = (const float*)d_in[0];
    const int*   ei     = (const int*)d_in[1];
    const float* Wself  = (const float*)d_in[2];
    const float* bself  = (const float*)d_in[3];
    const float* Wneigh = (const float*)d_in[4];
    const float* bneigh = (const float*)d_in[5];
    float* out = (float*)d_out;

    // Workspace layout (all regions 64B-aligned; PADN = 50176):
    int* cnt      = (int*)d_ws;                 // [0,      PADN)
    int* row_off  = cnt + PADN;                 // [PADN,   2*PADN)   needs N+1
    int* cursor   = row_off + PADN;             // [2*PADN, 3*PADN)
    int* edge_src = cursor + PADN;              // [3*PADN, 3*PADN+N_EDGES)
    float* mean   = (float*)(edge_src + N_EDGES); // N_NODES*DIM floats

    // Only cnt needs zeroing; everything else is fully written before read.
    hipMemsetAsync(cnt, 0, PADN * sizeof(int), stream);

    count_k<<<(N_EDGES + 255) / 256, 256, 0, stream>>>(ei, cnt);
    scan_k<<<1, 1024, 0, stream>>>(cnt, row_off, cursor);
    bucket_k<<<(N_EDGES + 255) / 256, 256, 0, stream>>>(ei, cursor, edge_src);
    gather_mean_k<<<(N_NODES + 7) / 8, 192, 0, stream>>>(x, row_off, edge_src, mean);
    sage_out_k<<<(N_NODES + NPB - 1) / NPB, 256, 0, stream>>>(
        x, mean, Wself, bself, Wneigh, bneigh, out);
}

// Round 3
// 251.962 us; speedup vs baseline: 4.7441x; 1.5963x over previous
//
#include <hip/hip_runtime.h>
#include <hip/hip_bf16.h>

#define N_NODES 50000
#define N_EDGES 800000
#define DIM 96
#define PADN 50176           // 196 * 256, covers N_NODES
#define SCAN_BLOCKS 196      // PADN / 256

__device__ __forceinline__ short f2bf(float f) {
    __hip_bfloat16 h = __float2bfloat16(f);
    return *reinterpret_cast<short*>(&h);
}

// ---------------------------------------------------------------------------
// K1: count degrees (int atomics)
// ---------------------------------------------------------------------------
__global__ __launch_bounds__(256) void count_k(
    const int* __restrict__ ei, int* __restrict__ cnt)
{
    int e = blockIdx.x * 256 + threadIdx.x;
    if (e >= N_EDGES) return;
    int t = ei[N_EDGES + e];
    atomicAdd(&cnt[t], 1);
}

// ---------------------------------------------------------------------------
// K2a: per-block inclusive scan of 256 counts; emit block sums
// ---------------------------------------------------------------------------
__global__ __launch_bounds__(256) void scan1_k(
    const int* __restrict__ cnt, int* __restrict__ incl, int* __restrict__ bsum)
{
    __shared__ int s[256];
    const int tid = threadIdx.x;
    const int i = blockIdx.x * 256 + tid;
    int v = (i < N_NODES) ? cnt[i] : 0;
    s[tid] = v;
    __syncthreads();
    for (int off = 1; off < 256; off <<= 1) {
        int t = (tid >= off) ? s[tid - off] : 0;
        __syncthreads();
        s[tid] += t;
        __syncthreads();
    }
    incl[i] = s[tid];
    if (tid == 255) bsum[blockIdx.x] = s[255];
}

// ---------------------------------------------------------------------------
// K2b: single small block scans the 196 block sums (exclusive)
// ---------------------------------------------------------------------------
__global__ __launch_bounds__(256) void scan2_k(
    const int* __restrict__ bsum, int* __restrict__ boff)
{
    __shared__ int s[256];
    const int tid = threadIdx.x;
    int v = (tid < SCAN_BLOCKS) ? bsum[tid] : 0;
    s[tid] = v;
    __syncthreads();
    for (int off = 1; off < 256; off <<= 1) {
        int t = (tid >= off) ? s[tid - off] : 0;
        __syncthreads();
        s[tid] += t;
        __syncthreads();
    }
    if (tid < SCAN_BLOCKS) boff[tid] = s[tid] - v;  // exclusive prefix
}

// ---------------------------------------------------------------------------
// K2c: apply -> row_off / cursor
// ---------------------------------------------------------------------------
__global__ __launch_bounds__(256) void scan3_k(
    const int* __restrict__ cnt, const int* __restrict__ incl,
    const int* __restrict__ boff, int* __restrict__ row_off, int* __restrict__ cursor)
{
    const int i = blockIdx.x * 256 + threadIdx.x;
    if (i == 0) row_off[N_NODES] = N_EDGES;
    if (i >= N_NODES) return;
    int excl = incl[i] - cnt[i] + boff[blockIdx.x];
    row_off[i] = excl;
    cursor[i] = excl;
}

// ---------------------------------------------------------------------------
// K3: bucket edges into CSR (int atomics on cursors)
// ---------------------------------------------------------------------------
__global__ __launch_bounds__(256) void bucket_k(
    const int* __restrict__ ei, int* __restrict__ cursor, int* __restrict__ edge_src)
{
    int e = blockIdx.x * 256 + threadIdx.x;
    if (e >= N_EDGES) return;
    int s = ei[e];
    int t = ei[N_EDGES + e];
    int pos = atomicAdd(&cursor[t], 1);
    edge_src[pos] = s;
}

// ---------------------------------------------------------------------------
// K4: gather-sum + mean. 24 threads per node (one float4 column each);
// block = 192 threads = 8 nodes.
// ---------------------------------------------------------------------------
__global__ __launch_bounds__(192) void gather_mean_k(
    const float* __restrict__ x,
    const int* __restrict__ row_off,
    const int* __restrict__ edge_src,
    float* __restrict__ mean)
{
    const int tid = threadIdx.x;
    const int g = tid / 24;
    const int l = tid - g * 24;
    const int node = blockIdx.x * 8 + g;
    if (node >= N_NODES) return;

    const int beg = row_off[node];
    const int end = row_off[node + 1];
    float4 acc = make_float4(0.f, 0.f, 0.f, 0.f);
    for (int i = beg; i < end; i++) {
        int s = edge_src[i];
        float4 v = *reinterpret_cast<const float4*>(x + (size_t)s * DIM + l * 4);
        acc.x += v.x; acc.y += v.y; acc.z += v.z; acc.w += v.w;
    }
    float inv = (end > beg) ? 1.0f / (float)(end - beg) : 0.0f;
    acc.x *= inv; acc.y *= inv; acc.z *= inv; acc.w *= inv;
    *reinterpret_cast<float4*>(mean + (size_t)node * DIM + l * 4) = acc;
}

// ---------------------------------------------------------------------------
// K5: out = [x | mean] @ [Wself^T ; Wneigh^T] + (bself + bneigh)
// bf16 MFMA 16x16x32. Block = 256 thr (4 waves) = 64 rows x 96 cols.
// LDS rows padded to 200 shorts (400 B) -> 2-way bank aliasing (free).
// Frag layouts (m89/m91-verified): A/B [idx=lane&15][k=(lane>>4)*8+j],
// C/D col=lane&15, row=(lane>>4)*4+reg.
// ---------------------------------------------------------------------------
__global__ __launch_bounds__(256) void sage_mfma_k(
    const float* __restrict__ x,
    const float* __restrict__ mean,
    const float* __restrict__ Wself,
    const float* __restrict__ bself,
    const float* __restrict__ Wneigh,
    const float* __restrict__ bneigh,
    float* __restrict__ out)
{
    using short8 = __attribute__((ext_vector_type(8))) short;
    using f32x4  = __attribute__((ext_vector_type(4))) float;

    __shared__ short Ab[64 * 200];  // [row][k0..191], stride 200
    __shared__ short Bb[96 * 200];  // [col][k0..191], stride 200
    const int tid = threadIdx.x;
    const int node0 = blockIdx.x * 64;

    // ---- Stage B: both weights, transposed-by-construction ----
    for (int idx = tid; idx < 96 * 96; idx += 256) {
        int j = idx / 96;           // output col
        int k = idx - j * 96;       // input dim
        Bb[j * 200 + k]      = f2bf(Wself[idx]);
        Bb[j * 200 + 96 + k] = f2bf(Wneigh[idx]);
    }
    // ---- Stage A: [x | mean] rows as bf16 ----
    for (int idx = tid; idx < 64 * 24; idx += 256) {
        int r  = idx / 24;
        int c4 = idx - r * 24;
        int node = node0 + r;
        float4 xv = make_float4(0.f, 0.f, 0.f, 0.f);
        float4 mv = make_float4(0.f, 0.f, 0.f, 0.f);
        if (node < N_NODES) {
            xv = *reinterpret_cast<const float4*>(x + (size_t)node * DIM + c4 * 4);
            mv = *reinterpret_cast<const float4*>(mean + (size_t)node * DIM + c4 * 4);
        }
        short* pa = &Ab[r * 200 + c4 * 4];
        pa[0] = f2bf(xv.x); pa[1] = f2bf(xv.y); pa[2] = f2bf(xv.z); pa[3] = f2bf(xv.w);
        short* pm = &Ab[r * 200 + 96 + c4 * 4];
        pm[0] = f2bf(mv.x); pm[1] = f2bf(mv.y); pm[2] = f2bf(mv.z); pm[3] = f2bf(mv.w);
    }
    __syncthreads();

    const int wave = tid >> 6;
    const int lane = tid & 63;
    const int quad = lane >> 4;
    const int m16  = lane & 15;
    const int rbase = wave * 16;

    f32x4 acc[6];
#pragma unroll
    for (int nt = 0; nt < 6; nt++) acc[nt] = (f32x4){0.f, 0.f, 0.f, 0.f};

#pragma unroll
    for (int kt = 0; kt < 6; kt++) {
        short8 a = *reinterpret_cast<const short8*>(&Ab[(rbase + m16) * 200 + kt * 32 + quad * 8]);
#pragma unroll
        for (int nt = 0; nt < 6; nt++) {
            short8 b = *reinterpret_cast<const short8*>(&Bb[(nt * 16 + m16) * 200 + kt * 32 + quad * 8]);
            acc[nt] = __builtin_amdgcn_mfma_f32_16x16x32_bf16(a, b, acc[nt], 0, 0, 0);
        }
    }

    // ---- Epilogue: bias + store (f32) ----
#pragma unroll
    for (int nt = 0; nt < 6; nt++) {
        int col = nt * 16 + m16;
        float bias = bself[col] + bneigh[col];
#pragma unroll
        for (int reg = 0; reg < 4; reg++) {
            int row = node0 + rbase + quad * 4 + reg;
            if (row < N_NODES)
                out[(size_t)row * DIM + col] = acc[nt][reg] + bias;
        }
    }
}

extern "C" void kernel_launch(void* const* d_in, const int* in_sizes, int n_in,
                              void* d_out, int out_size, void* d_ws, size_t ws_size,
                              hipStream_t stream) {
    const float* x      = (const float*)d_in[0];
    const int*   ei     = (const int*)d_in[1];
    const float* Wself  = (const float*)d_in[2];
    const float* bself  = (const float*)d_in[3];
    const float* Wneigh = (const float*)d_in[4];
    const float* bneigh = (const float*)d_in[5];
    float* out = (float*)d_out;

    // Workspace layout:
    int* cnt      = (int*)d_ws;                   // PADN
    int* incl     = cnt + PADN;                   // PADN
    int* row_off  = incl + PADN;                  // PADN (needs N+1)
    int* cursor   = row_off + PADN;               // PADN
    int* bsum     = cursor + PADN;                // 256
    int* boff     = bsum + 256;                   // 256
    int* edge_src = boff + 256;                   // N_EDGES
    float* mean   = (float*)(edge_src + N_EDGES); // N_NODES*DIM floats

    hipMemsetAsync(cnt, 0, PADN * sizeof(int), stream);

    count_k<<<(N_EDGES + 255) / 256, 256, 0, stream>>>(ei, cnt);
    scan1_k<<<SCAN_BLOCKS, 256, 0, stream>>>(cnt, incl, bsum);
    scan2_k<<<1, 256, 0, stream>>>(bsum, boff);
    scan3_k<<<SCAN_BLOCKS, 256, 0, stream>>>(cnt, incl, boff, row_off, cursor);
    bucket_k<<<(N_EDGES + 255) / 256, 256, 0, stream>>>(ei, cursor, edge_src);
    gather_mean_k<<<(N_NODES + 7) / 8, 192, 0, stream>>>(x, row_off, edge_src, mean);
    sage_mfma_k<<<(N_NODES + 63) / 64, 256, 0, stream>>>(
        x, mean, Wself, bself, Wneigh, bneigh, out);
}